// Round 14
// baseline (417.587 us; speedup 1.0000x reference)
//
#include <hip/hip_runtime.h>
#include <hip/hip_fp16.h>
#include <math.h>

#define N_NODES 100000
#define N_EDGES 3200000
#define IN_CH   256
#define HID     64
#define OUTC    32
#define NB      ((N_NODES + 255) / 256)   // 391 scan blocks
#define NBUCK   ((N_NODES + 127) / 128)   // 782 buckets of 128 nodes (bucket = dst >> 7)
#define CHUNK   4096                      // edges per partition block
#define EPT     16                        // edges per thread (CHUNK/256)
#define CAP     4608                      // bucket capacity: mean 4092, sigma ~64 -> +8 sigma

// ---------------- workspace layout (bytes) ----------------
static constexpr size_t align256(size_t x) { return (x + 255) & ~(size_t)255; }
static constexpr size_t OFF_DEG  = 0;                                          // N ints
static constexpr size_t OFF_PTR  = OFF_DEG  + align256((size_t)N_NODES * 4);   // N ints (exclusive)
static constexpr size_t OFF_BSUM = OFF_PTR  + align256((size_t)N_NODES * 4);   // 512 ints
static constexpr size_t OFF_GCUR = OFF_BSUM + align256(512 * 4);               // NBUCK ints
static constexpr size_t OFF_DIS  = OFF_GCUR + align256((size_t)NBUCK * 4);     // N floats
static constexpr size_t OFF_SRC  = OFF_DIS  + align256((size_t)N_NODES * 4);   // E ints
static constexpr size_t OFF_PART = OFF_SRC  + align256((size_t)N_EDGES * 4);   // NBUCK*CAP ints (14.4 MB)
// s1h (N*64 halves = 12.8 MB) aliases PART (part dead after bucket_fill, before gemm1)
static constexpr size_t OFF_S1   = OFF_PART;
static constexpr size_t OFF_S2   = OFF_PART + align256((size_t)NBUCK * CAP * 4);  // N*32 halves (6.4 MB)
// total ~50 MB

// ---------------- bucket cursor init: gcur[b] = b*CAP ----------------
__global__ __launch_bounds__(256) void bucket_init(int* __restrict__ gcur) {
    int b = blockIdx.x * 256 + threadIdx.x;
    if (b < NBUCK) gcur[b] = b * CAP;
}

// ---------------- phase A: partition edges into dst-buckets (single pass) --------
__global__ __launch_bounds__(256) void partition_edges(const int* __restrict__ row,
                                                       const int* __restrict__ col,
                                                       int* __restrict__ gcur,
                                                       int* __restrict__ part) {
    __shared__ int lhist[NBUCK];
    __shared__ int lbase[NBUCK];
    const int t  = threadIdx.x;
    const int e0 = blockIdx.x * CHUNK;
    for (int i = t; i < NBUCK; i += 256) lhist[i] = 0;
    __syncthreads();

    int pk[EPT], br[EPT];
#pragma unroll
    for (int i = 0; i < EPT; ++i) {
        int e = e0 + i * 256 + t;
        if (e < N_EDGES) {
            int d = col[e];
            int b = d >> 7;
            int r = atomicAdd(&lhist[b], 1);
            pk[i] = row[e] | ((d & 127) << 17);
            br[i] = b | (r << 10);           // b<1024, r<4096 -> fits
        } else {
            br[i] = -1;
        }
    }
    __syncthreads();

    const int off = (int)((blockIdx.x * 131u) % NBUCK);
    for (int i = t; i < NBUCK; i += 256) {
        int bb = i + off;
        if (bb >= NBUCK) bb -= NBUCK;
        int c = lhist[bb];
        lbase[bb] = (c > 0) ? atomicAdd(&gcur[bb], c) : 0;
    }
    __syncthreads();

#pragma unroll
    for (int i = 0; i < EPT; ++i) {
        if (br[i] >= 0) {
            int b = br[i] & 1023;
            int r = br[i] >> 10;
            part[lbase[b] + r] = pk[i];
        }
    }
}

// ---------------- phase B1: per-node degree + dis from bucket data ---------------
__global__ __launch_bounds__(256) void bucket_hist(const int* __restrict__ gcur,
                                                   const int* __restrict__ part,
                                                   int* __restrict__ deg,
                                                   float* __restrict__ dis) {
    __shared__ int lh[128];
    const int b = blockIdx.x;
    const int t = threadIdx.x;
    if (t < 128) lh[t] = 0;
    __syncthreads();
    const int cnt = gcur[b] - b * CAP;
    for (int i = t; i < cnt; i += 256)
        atomicAdd(&lh[part[(size_t)b * CAP + i] >> 17], 1);
    __syncthreads();
    int v = b * 128 + t;
    if (t < 128 && v < N_NODES) {
        int d = lh[t];
        deg[v] = d;
        dis[v] = rsqrtf((float)d + 1.0f);   // +1 self-loop
    }
}

// ---------------- 3-kernel exclusive scan of deg -> ptr ----------------
__global__ __launch_bounds__(256) void scan_block_sums(const int* __restrict__ deg,
                                                       int* __restrict__ bsum) {
    __shared__ int buf[256];
    unsigned i = blockIdx.x * 256u + threadIdx.x;
    int v = (i < N_NODES) ? deg[i] : 0;
    buf[threadIdx.x] = v;
    __syncthreads();
    for (int off = 128; off > 0; off >>= 1) {
        if (threadIdx.x < (unsigned)off) buf[threadIdx.x] += buf[threadIdx.x + off];
        __syncthreads();
    }
    if (threadIdx.x == 0) bsum[blockIdx.x] = buf[0];
}

__global__ __launch_bounds__(512) void scan_bsum(int* __restrict__ bsum) {
    __shared__ int buf[512];
    int t = threadIdx.x;
    int v = (t < NB) ? bsum[t] : 0;
    buf[t] = v;
    __syncthreads();
    for (int off = 1; off < 512; off <<= 1) {
        int add = (t >= off) ? buf[t - off] : 0;
        __syncthreads();
        buf[t] += add;
        __syncthreads();
    }
    if (t < NB) bsum[t] = buf[t] - v;  // exclusive
}

__global__ __launch_bounds__(256) void scan_block_scan(const int* __restrict__ deg,
                                                       const int* __restrict__ bsum,
                                                       int* __restrict__ ptr) {
    __shared__ int buf[256];
    unsigned i = blockIdx.x * 256u + threadIdx.x;
    int v = (i < N_NODES) ? deg[i] : 0;
    buf[threadIdx.x] = v;
    __syncthreads();
    for (int off = 1; off < 256; off <<= 1) {
        int add = (threadIdx.x >= (unsigned)off) ? buf[threadIdx.x - off] : 0;
        __syncthreads();
        buf[threadIdx.x] += add;
        __syncthreads();
    }
    if (i < N_NODES) ptr[i] = bsum[blockIdx.x] + buf[threadIdx.x] - v;  // exclusive
}

// ---------------- phase B2: fill srcs; writes confined to ~16KB window/block -------
__global__ __launch_bounds__(256) void bucket_fill(const int* __restrict__ gcur,
                                                   const int* __restrict__ part,
                                                   const int* __restrict__ ptr,
                                                   int* __restrict__ srcs) {
    __shared__ int lcur[128];
    const int b = blockIdx.x;
    const int t = threadIdx.x;
    if (t < 128) lcur[t] = 0;
    __syncthreads();
    const int cnt = gcur[b] - b * CAP;
    for (int i = t; i < cnt; i += 256) {
        int p    = part[(size_t)b * CAP + i];
        int dlow = p >> 17;
        int src  = p & 0x1FFFF;
        int r    = atomicAdd(&lcur[dlow], 1);        // LDS cursor
        srcs[ptr[b * 128 + dlow] + r] = src;
    }
}

// ---------------- GEMM1: s1h[n][j] = fp16(dis[n] * (x[n,:] @ W1[:,j])) ----------
// r11 version (71 us): serial stage->barrier->compute->barrier.
__global__ __launch_bounds__(256) void gemm1(const float* __restrict__ x,
                                             const float* __restrict__ W1,
                                             const float* __restrict__ dis,
                                             __half* __restrict__ s1h) {
    __shared__ float wlds[64 * HID];   // 16 KB k-chunk of W1: [k_local][j]
    __shared__ float xlds[64 * 68];    // 17 KB x-tile: [row_local][k_local], stride 68

    const int t  = threadIdx.x;
    const int tx = t & 15;
    const int ty = t >> 4;
    const int row0 = blockIdx.x * 64;

    float acc[4][4] = {{0.f}};

    for (int kt = 0; kt < IN_CH / 64; ++kt) {
        {
            const float4* w4 = (const float4*)(W1 + (size_t)kt * 64 * HID);
            float4* l4 = (float4*)wlds;
#pragma unroll
            for (int i = 0; i < 4; ++i) l4[i * 256 + t] = w4[i * 256 + t];
        }
        {
#pragma unroll
            for (int i = 0; i < 4; ++i) {
                int L  = i * 256 + t;
                int rl = L >> 4;
                int k4 = L & 15;
                int rg = row0 + rl;
                float4 v;
                if (rg < N_NODES) v = ((const float4*)x)[(size_t)rg * 64 + kt * 16 + k4];
                else              v = make_float4(0.f, 0.f, 0.f, 0.f);
                *(float4*)(&xlds[rl * 68 + k4 * 4]) = v;
            }
        }
        __syncthreads();

        const float4* wl4 = (const float4*)wlds;
#pragma unroll 4
        for (int k4 = 0; k4 < 16; ++k4) {
            float4 xv[4];
#pragma unroll
            for (int i = 0; i < 4; ++i)
                xv[i] = *(const float4*)(&xlds[(ty * 4 + i) * 68 + k4 * 4]);
#pragma unroll
            for (int kk = 0; kk < 4; ++kk) {
                float4 bv = wl4[(k4 * 4 + kk) * 16 + tx];
#pragma unroll
                for (int i = 0; i < 4; ++i) {
                    const float* xf = (const float*)&xv[i];
                    float a = xf[kk];
                    acc[i][0] += a * bv.x;
                    acc[i][1] += a * bv.y;
                    acc[i][2] += a * bv.z;
                    acc[i][3] += a * bv.w;
                }
            }
        }
        __syncthreads();
    }

#pragma unroll
    for (int i = 0; i < 4; ++i) {
        int rr = row0 + ty * 4 + i;
        if (rr < N_NODES) {
            float d = dis[rr];
            __half2 p0 = __floats2half2_rn(acc[i][0] * d, acc[i][1] * d);
            __half2 p1 = __floats2half2_rn(acc[i][2] * d, acc[i][3] * d);
            __half2* dst = (__half2*)(s1h + (size_t)rr * HID + tx * 4);
            dst[0] = p0;
            dst[1] = p1;
        }
    }
}

// ---------------- gather1 + ELU + fused GEMM2 -------------------------------------
// 2 EDGES PER VMEM INSTRUCTION: lane l=j&31 covers features (2l,2l+1) via one
// __half2 (dword) load; half-wave h=j>>5 selects edge-of-pair. One instruction
// moves 2 rows (256 B) vs 1 row before -> 0.5 instr/edge. Partials combined
// with shfl_xor(32). Fused gemm2 epilogue unchanged in math.
__global__ __launch_bounds__(256) void gather1(const __half* __restrict__ s1h,
                                               const int* __restrict__ ptr,
                                               const int* __restrict__ srcs,
                                               const float* __restrict__ dis,
                                               const float* __restrict__ b1,
                                               const float* __restrict__ W2,
                                               __half* __restrict__ s2h) {
    __shared__ float w2lds[HID * OUTC];   // 8 KB: [k][jo]
    __shared__ float hbuf[4][HID];        // per-wave ELU'd h row

    const int t = threadIdx.x;
    {
        float4* l4 = (float4*)w2lds;
        const float4* s4 = (const float4*)W2;
        l4[t] = s4[t];
        l4[256 + t] = s4[256 + t];
    }
    __syncthreads();

    const int j = t & 63;
    const int w = t >> 6;
    const int l = j & 31;                 // half2 index within row (features 2l,2l+1)
    const int h = j >> 5;                 // edge-of-pair selector
    const int v = __builtin_amdgcn_readfirstlane(blockIdx.x * 4 + w);
    const __half2* s12 = (const __half2*)s1h;   // row stride 32 half2

    float2 acc;
    {
        float2 self = __half22float2(s12[(size_t)v * 32 + l]);
        acc = (h == 0) ? self : make_float2(0.f, 0.f);   // self-loop counted once
    }
    const int beg = ptr[v];
    const int end = (v + 1 < N_NODES) ? ptr[v + 1] : N_EDGES;
    int k = beg;
    for (; k + 8 <= end; k += 8) {
        int u0 = srcs[k],     u1 = srcs[k + 1], u2 = srcs[k + 2], u3 = srcs[k + 3];
        int u4 = srcs[k + 4], u5 = srcs[k + 5], u6 = srcs[k + 6], u7 = srcs[k + 7];
        int a0 = (h == 0) ? u0 : u1;
        int a1 = (h == 0) ? u2 : u3;
        int a2 = (h == 0) ? u4 : u5;
        int a3 = (h == 0) ? u6 : u7;
        float2 g0 = __half22float2(s12[(size_t)a0 * 32 + l]);
        float2 g1 = __half22float2(s12[(size_t)a1 * 32 + l]);
        float2 g2 = __half22float2(s12[(size_t)a2 * 32 + l]);
        float2 g3 = __half22float2(s12[(size_t)a3 * 32 + l]);
        acc.x += (g0.x + g1.x) + (g2.x + g3.x);
        acc.y += (g0.y + g1.y) + (g2.y + g3.y);
    }
    for (; k + 2 <= end; k += 2) {
        int u0 = srcs[k], u1 = srcs[k + 1];
        int a = (h == 0) ? u0 : u1;
        float2 g = __half22float2(s12[(size_t)a * 32 + l]);
        acc.x += g.x;
        acc.y += g.y;
    }
    if (k < end && h == 0) {
        float2 g = __half22float2(s12[(size_t)srcs[k] * 32 + l]);
        acc.x += g.x;
        acc.y += g.y;
    }
    acc.x += __shfl_xor(acc.x, 32, 64);   // even-edge + odd-edge partials
    acc.y += __shfl_xor(acc.y, 32, 64);

    float dv = dis[v];
    float2 bb = *(const float2*)(b1 + 2 * l);
    float t0 = dv * acc.x + bb.x;
    float t1 = dv * acc.y + bb.y;
    float h0 = t0 > 0.f ? t0 : (expf(t0) - 1.f);
    float h1 = t1 > 0.f ? t1 : (expf(t1) - 1.f);
    if (h == 0) {
        hbuf[w][2 * l]     = h0;
        hbuf[w][2 * l + 1] = h1;
    }

    // ---- fused gemm2: s2[v][jo] = dis[v] * sum_k hh[k] * W2[k][jo]
    const int jo = j & 31;
    const int kb = (j >> 5) * 32;          // lower lanes: k 0..31, upper: 32..63
    float p = 0.f;
#pragma unroll
    for (int kk = 0; kk < 32; ++kk)
        p += hbuf[w][kb + kk] * w2lds[(kb + kk) * OUTC + jo];
    p += __shfl_xor(p, 32, 64);            // combine the two k-halves
    if (j < 32) {
        s2h[(size_t)v * OUTC + jo] = __float2half(dv * p);
    }
}

// ---------------- gather2 + ELU + final projection --------------------------------
// 4 EDGES PER VMEM INSTRUCTION: one wave per node; lane l=j&15 covers features
// (2l,2l+1), quad q=j>>4 selects edge-of-quad. One instruction moves 4 rows
// (256 B, each row exactly one 64 B line). Combine with shfl_xor(16)+(32).
__global__ __launch_bounds__(256) void gather2(const __half* __restrict__ s2h,
                                               const int* __restrict__ ptr,
                                               const int* __restrict__ srcs,
                                               const float* __restrict__ dis,
                                               const float* __restrict__ b2,
                                               const float* __restrict__ Wc,
                                               const float* __restrict__ bc,
                                               float* __restrict__ out) {
    const int j = threadIdx.x & 63;
    const int w = threadIdx.x >> 6;
    const int l = j & 15;                 // half2 index within row
    const int q = j >> 4;                 // edge-of-quad selector
    const int v = __builtin_amdgcn_readfirstlane(blockIdx.x * 4 + w);
    const __half2* s22 = (const __half2*)s2h;   // row stride 16 half2

    float2 acc;
    {
        float2 self = __half22float2(s22[(size_t)v * 16 + l]);
        acc = (q == 0) ? self : make_float2(0.f, 0.f);
    }
    const int beg = ptr[v];
    const int end = (v + 1 < N_NODES) ? ptr[v + 1] : N_EDGES;
    int k = beg;
    for (; k + 8 <= end; k += 8) {
        int a0 = srcs[k + q];
        int a1 = srcs[k + 4 + q];
        float2 g0 = __half22float2(s22[(size_t)a0 * 16 + l]);
        float2 g1 = __half22float2(s22[(size_t)a1 * 16 + l]);
        acc.x += g0.x + g1.x;
        acc.y += g0.y + g1.y;
    }
    for (; k + 4 <= end; k += 4) {
        int a = srcs[k + q];
        float2 g = __half22float2(s22[(size_t)a * 16 + l]);
        acc.x += g.x;
        acc.y += g.y;
    }
    int rem = end - k;
    if (q < rem) {
        int a = srcs[k + q];
        float2 g = __half22float2(s22[(size_t)a * 16 + l]);
        acc.x += g.x;
        acc.y += g.y;
    }
    acc.x += __shfl_xor(acc.x, 16, 64);
    acc.x += __shfl_xor(acc.x, 32, 64);
    acc.y += __shfl_xor(acc.y, 16, 64);
    acc.y += __shfl_xor(acc.y, 32, 64);

    float dv = dis[v];
    float2 bb = *(const float2*)(b2 + 2 * l);
    float t0 = dv * acc.x + bb.x;
    float t1 = dv * acc.y + bb.y;
    float h0 = t0 > 0.f ? t0 : (expf(t0) - 1.f);
    float h1 = t1 > 0.f ? t1 : (expf(t1) - 1.f);
    float2 wc = *(const float2*)(Wc + 2 * l);
    float p = h0 * wc.x + h1 * wc.y;
#pragma unroll
    for (int off = 8; off > 0; off >>= 1) p += __shfl_xor(p, off, 64);  // sum over 16 lanes
    if (j == 0) out[v] = p + bc[0];
}

extern "C" void kernel_launch(void* const* d_in, const int* in_sizes, int n_in,
                              void* d_out, int out_size, void* d_ws, size_t ws_size,
                              hipStream_t stream) {
    const float* x  = (const float*)d_in[0];
    const int*   ei = (const int*)d_in[1];
    const float* W1 = (const float*)d_in[2];
    const float* b1 = (const float*)d_in[3];
    const float* W2 = (const float*)d_in[4];
    const float* b2 = (const float*)d_in[5];
    const float* Wc = (const float*)d_in[6];
    const float* bc = (const float*)d_in[7];
    float* out = (float*)d_out;

    const int* row = ei;            // edge_index[0] = source
    const int* col = ei + N_EDGES;  // edge_index[1] = target

    char* ws = (char*)d_ws;
    int*    deg  = (int*)   (ws + OFF_DEG);
    int*    ptr  = (int*)   (ws + OFF_PTR);
    int*    bsum = (int*)   (ws + OFF_BSUM);
    int*    gcur = (int*)   (ws + OFF_GCUR);
    float*  dis  = (float*) (ws + OFF_DIS);
    int*    srcs = (int*)   (ws + OFF_SRC);
    int*    part = (int*)   (ws + OFF_PART);
    __half* s1h  = (__half*)(ws + OFF_S1);    // aliases part (part dead before gemm1)
    __half* s2h  = (__half*)(ws + OFF_S2);

    bucket_init    <<<(NBUCK + 255) / 256, 256, 0, stream>>>(gcur);
    partition_edges<<<(N_EDGES + CHUNK - 1) / CHUNK, 256, 0, stream>>>(row, col, gcur, part);
    bucket_hist    <<<NBUCK, 256, 0, stream>>>(gcur, part, deg, dis);
    scan_block_sums<<<NB, 256, 0, stream>>>(deg, bsum);
    scan_bsum      <<<1, 512, 0, stream>>>(bsum);
    scan_block_scan<<<NB, 256, 0, stream>>>(deg, bsum, ptr);
    bucket_fill    <<<NBUCK, 256, 0, stream>>>(gcur, part, ptr, srcs);

    gemm1  <<<(N_NODES + 63) / 64, 256, 0, stream>>>(x, W1, dis, s1h);
    gather1<<<N_NODES / 4, 256, 0, stream>>>(s1h, ptr, srcs, dis, b1, W2, s2h);
    gather2<<<N_NODES / 4, 256, 0, stream>>>(s2h, ptr, srcs, dis, b2, Wc, bc, out);
}

// Round 15
// 414.531 us; speedup vs baseline: 1.0074x; 1.0074x over previous
//
#include <hip/hip_runtime.h>
#include <hip/hip_fp16.h>
#include <math.h>

#define N_NODES 100000
#define N_EDGES 3200000
#define IN_CH   256
#define HID     64
#define OUTC    32
#define NBUCK   ((N_NODES + 127) / 128)   // 782 buckets of 128 nodes (bucket = dst >> 7)
#define CHUNK   4096                      // edges per partition block
#define EPT     16                        // edges per thread (CHUNK/256)
#define CAP     4608                      // bucket capacity: mean 4092, sigma ~64 -> +8 sigma

// ---------------- workspace layout (bytes) ----------------
static constexpr size_t align256(size_t x) { return (x + 255) & ~(size_t)255; }
static constexpr size_t OFF_PTRB = 0;                                          // N ints (segment start, bucket-local CSR)
static constexpr size_t OFF_PTRE = OFF_PTRB + align256((size_t)N_NODES * 4);   // N ints (segment end)
static constexpr size_t OFF_GCUR = OFF_PTRE + align256((size_t)N_NODES * 4);   // NBUCK ints
static constexpr size_t OFF_DIS  = OFF_GCUR + align256((size_t)NBUCK * 4);     // N floats
static constexpr size_t OFF_SRC  = OFF_DIS  + align256((size_t)N_NODES * 4);   // NBUCK*CAP ints (14.4 MB, bucket-padded)
static constexpr size_t OFF_PART = OFF_SRC  + align256((size_t)NBUCK * CAP * 4); // NBUCK*CAP ints (14.4 MB)
// s1h (N*64 halves = 12.8 MB) aliases PART (part dead after bucket_fill, before gemm1)
static constexpr size_t OFF_S1   = OFF_PART;
static constexpr size_t OFF_S2   = OFF_PART + align256((size_t)NBUCK * CAP * 4);  // N*32 halves (6.4 MB)
// total ~52 MB

// ---------------- bucket cursor init: gcur[b] = b*CAP ----------------
__global__ __launch_bounds__(256) void bucket_init(int* __restrict__ gcur) {
    int b = blockIdx.x * 256 + threadIdx.x;
    if (b < NBUCK) gcur[b] = b * CAP;
}

// ---------------- phase A: partition edges into dst-buckets (single pass) --------
__global__ __launch_bounds__(256) void partition_edges(const int* __restrict__ row,
                                                       const int* __restrict__ col,
                                                       int* __restrict__ gcur,
                                                       int* __restrict__ part) {
    __shared__ int lhist[NBUCK];
    __shared__ int lbase[NBUCK];
    const int t  = threadIdx.x;
    const int e0 = blockIdx.x * CHUNK;
    for (int i = t; i < NBUCK; i += 256) lhist[i] = 0;
    __syncthreads();

    int pk[EPT], br[EPT];
#pragma unroll
    for (int i = 0; i < EPT; ++i) {
        int e = e0 + i * 256 + t;
        if (e < N_EDGES) {
            int d = col[e];
            int b = d >> 7;
            int r = atomicAdd(&lhist[b], 1);
            pk[i] = row[e] | ((d & 127) << 17);
            br[i] = b | (r << 10);           // b<1024, r<4096 -> fits
        } else {
            br[i] = -1;
        }
    }
    __syncthreads();

    const int off = (int)((blockIdx.x * 131u) % NBUCK);
    for (int i = t; i < NBUCK; i += 256) {
        int bb = i + off;
        if (bb >= NBUCK) bb -= NBUCK;
        int c = lhist[bb];
        lbase[bb] = (c > 0) ? atomicAdd(&gcur[bb], c) : 0;
    }
    __syncthreads();

#pragma unroll
    for (int i = 0; i < EPT; ++i) {
        if (br[i] >= 0) {
            int b = br[i] & 1023;
            int r = br[i] >> 10;
            part[lbase[b] + r] = pk[i];
        }
    }
}

// ---------------- phase B1: histogram + LDS scan -> bucket-local CSR ptrs --------
// Replaces the 3-kernel global scan: per-node segments live inside the bucket's
// padded [b*CAP, b*CAP+cnt) region of srcs; ptrb/ptre give start/end directly.
__global__ __launch_bounds__(256) void bucket_hist(const int* __restrict__ gcur,
                                                   const int* __restrict__ part,
                                                   int* __restrict__ ptrb,
                                                   int* __restrict__ ptre,
                                                   float* __restrict__ dis) {
    __shared__ int lh[128];
    __shared__ int ls[128];
    const int b = blockIdx.x;
    const int t = threadIdx.x;
    if (t < 128) lh[t] = 0;
    __syncthreads();
    const int cnt = gcur[b] - b * CAP;
    for (int i = t; i < cnt; i += 256)
        atomicAdd(&lh[part[(size_t)b * CAP + i] >> 17], 1);
    __syncthreads();
    int val = (t < 128) ? lh[t] : 0;
    if (t < 128) ls[t] = val;
    __syncthreads();
    for (int off = 1; off < 128; off <<= 1) {
        int add = (t >= off && t < 128) ? ls[t - off] : 0;
        __syncthreads();
        if (t < 128) ls[t] += add;
        __syncthreads();
    }
    int v = b * 128 + t;
    if (t < 128 && v < N_NODES) {
        int excl = ls[t] - val;
        ptrb[v] = b * CAP + excl;
        ptre[v] = b * CAP + excl + val;
        dis[v]  = rsqrtf((float)val + 1.0f);   // +1 self-loop
    }
}

// ---------------- phase B2: fill srcs (bucket-local; ~18KB write window/block) ----
__global__ __launch_bounds__(256) void bucket_fill(const int* __restrict__ gcur,
                                                   const int* __restrict__ part,
                                                   const int* __restrict__ ptrb,
                                                   int* __restrict__ srcs) {
    __shared__ int lcur[128];
    __shared__ int lbase2[128];
    const int b = blockIdx.x;
    const int t = threadIdx.x;
    if (t < 128) {
        lcur[t] = 0;
        int v = b * 128 + t;
        lbase2[t] = (v < N_NODES) ? ptrb[v] : 0;
    }
    __syncthreads();
    const int cnt = gcur[b] - b * CAP;
    for (int i = t; i < cnt; i += 256) {
        int p    = part[(size_t)b * CAP + i];
        int dlow = p >> 17;
        int src  = p & 0x1FFFF;
        int r    = atomicAdd(&lcur[dlow], 1);        // LDS cursor
        srcs[lbase2[dlow] + r] = src;
    }
}

// ---------------- GEMM1: s1h[n][j] = fp16(dis[n] * (x[n,:] @ W1[:,j])) ----------
__global__ __launch_bounds__(256) void gemm1(const float* __restrict__ x,
                                             const float* __restrict__ W1,
                                             const float* __restrict__ dis,
                                             __half* __restrict__ s1h) {
    __shared__ float wlds[64 * HID];   // 16 KB k-chunk of W1: [k_local][j]
    __shared__ float xlds[64 * 68];    // 17 KB x-tile: [row_local][k_local], stride 68

    const int t  = threadIdx.x;
    const int tx = t & 15;
    const int ty = t >> 4;
    const int row0 = blockIdx.x * 64;

    float acc[4][4] = {{0.f}};

    for (int kt = 0; kt < IN_CH / 64; ++kt) {
        {
            const float4* w4 = (const float4*)(W1 + (size_t)kt * 64 * HID);
            float4* l4 = (float4*)wlds;
#pragma unroll
            for (int i = 0; i < 4; ++i) l4[i * 256 + t] = w4[i * 256 + t];
        }
        {
#pragma unroll
            for (int i = 0; i < 4; ++i) {
                int L  = i * 256 + t;
                int rl = L >> 4;
                int k4 = L & 15;
                int rg = row0 + rl;
                float4 v;
                if (rg < N_NODES) v = ((const float4*)x)[(size_t)rg * 64 + kt * 16 + k4];
                else              v = make_float4(0.f, 0.f, 0.f, 0.f);
                *(float4*)(&xlds[rl * 68 + k4 * 4]) = v;
            }
        }
        __syncthreads();

        const float4* wl4 = (const float4*)wlds;
#pragma unroll 4
        for (int k4 = 0; k4 < 16; ++k4) {
            float4 xv[4];
#pragma unroll
            for (int i = 0; i < 4; ++i)
                xv[i] = *(const float4*)(&xlds[(ty * 4 + i) * 68 + k4 * 4]);
#pragma unroll
            for (int kk = 0; kk < 4; ++kk) {
                float4 bv = wl4[(k4 * 4 + kk) * 16 + tx];
#pragma unroll
                for (int i = 0; i < 4; ++i) {
                    const float* xf = (const float*)&xv[i];
                    float a = xf[kk];
                    acc[i][0] += a * bv.x;
                    acc[i][1] += a * bv.y;
                    acc[i][2] += a * bv.z;
                    acc[i][3] += a * bv.w;
                }
            }
        }
        __syncthreads();
    }

#pragma unroll
    for (int i = 0; i < 4; ++i) {
        int rr = row0 + ty * 4 + i;
        if (rr < N_NODES) {
            float d = dis[rr];
            __half2 p0 = __floats2half2_rn(acc[i][0] * d, acc[i][1] * d);
            __half2 p1 = __floats2half2_rn(acc[i][2] * d, acc[i][3] * d);
            __half2* dst = (__half2*)(s1h + (size_t)rr * HID + tx * 4);
            dst[0] = p0;
            dst[1] = p1;
        }
    }
}

// ---------------- gather1 + ELU + fused GEMM2 -------------------------------------
// 2 edges/VMEM-instr; 16-edge unroll -> 8 packed loads in flight (latency hiding).
__global__ __launch_bounds__(256) void gather1(const __half* __restrict__ s1h,
                                               const int* __restrict__ ptrb,
                                               const int* __restrict__ ptre,
                                               const int* __restrict__ srcs,
                                               const float* __restrict__ dis,
                                               const float* __restrict__ b1,
                                               const float* __restrict__ W2,
                                               __half* __restrict__ s2h) {
    __shared__ float w2lds[HID * OUTC];   // 8 KB: [k][jo]
    __shared__ float hbuf[4][HID];        // per-wave ELU'd h row

    const int t = threadIdx.x;
    {
        float4* l4 = (float4*)w2lds;
        const float4* s4 = (const float4*)W2;
        l4[t] = s4[t];
        l4[256 + t] = s4[256 + t];
    }
    __syncthreads();

    const int j = t & 63;
    const int w = t >> 6;
    const int l = j & 31;                 // half2 index within row (features 2l,2l+1)
    const int h = j >> 5;                 // edge-of-pair selector
    const int v = __builtin_amdgcn_readfirstlane(blockIdx.x * 4 + w);
    const __half2* s12 = (const __half2*)s1h;   // row stride 32 half2

    float2 acc;
    {
        float2 self = __half22float2(s12[(size_t)v * 32 + l]);
        acc = (h == 0) ? self : make_float2(0.f, 0.f);   // self-loop counted once
    }
    const int beg = ptrb[v];
    const int end = ptre[v];
    int k = beg;
    for (; k + 16 <= end; k += 16) {
        int a0 = (h == 0) ? srcs[k]      : srcs[k + 1];
        int a1 = (h == 0) ? srcs[k + 2]  : srcs[k + 3];
        int a2 = (h == 0) ? srcs[k + 4]  : srcs[k + 5];
        int a3 = (h == 0) ? srcs[k + 6]  : srcs[k + 7];
        int a4 = (h == 0) ? srcs[k + 8]  : srcs[k + 9];
        int a5 = (h == 0) ? srcs[k + 10] : srcs[k + 11];
        int a6 = (h == 0) ? srcs[k + 12] : srcs[k + 13];
        int a7 = (h == 0) ? srcs[k + 14] : srcs[k + 15];
        float2 g0 = __half22float2(s12[(size_t)a0 * 32 + l]);
        float2 g1 = __half22float2(s12[(size_t)a1 * 32 + l]);
        float2 g2 = __half22float2(s12[(size_t)a2 * 32 + l]);
        float2 g3 = __half22float2(s12[(size_t)a3 * 32 + l]);
        float2 g4 = __half22float2(s12[(size_t)a4 * 32 + l]);
        float2 g5 = __half22float2(s12[(size_t)a5 * 32 + l]);
        float2 g6 = __half22float2(s12[(size_t)a6 * 32 + l]);
        float2 g7 = __half22float2(s12[(size_t)a7 * 32 + l]);
        acc.x += ((g0.x + g1.x) + (g2.x + g3.x)) + ((g4.x + g5.x) + (g6.x + g7.x));
        acc.y += ((g0.y + g1.y) + (g2.y + g3.y)) + ((g4.y + g5.y) + (g6.y + g7.y));
    }
    for (; k + 2 <= end; k += 2) {
        int a = (h == 0) ? srcs[k] : srcs[k + 1];
        float2 g = __half22float2(s12[(size_t)a * 32 + l]);
        acc.x += g.x;
        acc.y += g.y;
    }
    if (k < end && h == 0) {
        float2 g = __half22float2(s12[(size_t)srcs[k] * 32 + l]);
        acc.x += g.x;
        acc.y += g.y;
    }
    acc.x += __shfl_xor(acc.x, 32, 64);   // even-edge + odd-edge partials
    acc.y += __shfl_xor(acc.y, 32, 64);

    float dv = dis[v];
    float2 bb = *(const float2*)(b1 + 2 * l);
    float t0 = dv * acc.x + bb.x;
    float t1 = dv * acc.y + bb.y;
    float h0 = t0 > 0.f ? t0 : (expf(t0) - 1.f);
    float h1 = t1 > 0.f ? t1 : (expf(t1) - 1.f);
    if (h == 0) {
        hbuf[w][2 * l]     = h0;
        hbuf[w][2 * l + 1] = h1;
    }

    // ---- fused gemm2: s2[v][jo] = dis[v] * sum_k hh[k] * W2[k][jo]
    const int jo = j & 31;
    const int kb = (j >> 5) * 32;          // lower lanes: k 0..31, upper: 32..63
    float p = 0.f;
#pragma unroll
    for (int kk = 0; kk < 32; ++kk)
        p += hbuf[w][kb + kk] * w2lds[(kb + kk) * OUTC + jo];
    p += __shfl_xor(p, 32, 64);            // combine the two k-halves
    if (j < 32) {
        s2h[(size_t)v * OUTC + jo] = __float2half(dv * p);
    }
}

// ---------------- gather2 + ELU + final projection --------------------------------
// 4 edges/VMEM-instr; 16-edge unroll -> 4 quad-loads in flight.
__global__ __launch_bounds__(256) void gather2(const __half* __restrict__ s2h,
                                               const int* __restrict__ ptrb,
                                               const int* __restrict__ ptre,
                                               const int* __restrict__ srcs,
                                               const float* __restrict__ dis,
                                               const float* __restrict__ b2,
                                               const float* __restrict__ Wc,
                                               const float* __restrict__ bc,
                                               float* __restrict__ out) {
    const int j = threadIdx.x & 63;
    const int w = threadIdx.x >> 6;
    const int l = j & 15;                 // half2 index within row
    const int q = j >> 4;                 // edge-of-quad selector
    const int v = __builtin_amdgcn_readfirstlane(blockIdx.x * 4 + w);
    const __half2* s22 = (const __half2*)s2h;   // row stride 16 half2

    float2 acc;
    {
        float2 self = __half22float2(s22[(size_t)v * 16 + l]);
        acc = (q == 0) ? self : make_float2(0.f, 0.f);
    }
    const int beg = ptrb[v];
    const int end = ptre[v];
    int k = beg;
    for (; k + 16 <= end; k += 16) {
        int a0 = srcs[k + q];
        int a1 = srcs[k + 4 + q];
        int a2 = srcs[k + 8 + q];
        int a3 = srcs[k + 12 + q];
        float2 g0 = __half22float2(s22[(size_t)a0 * 16 + l]);
        float2 g1 = __half22float2(s22[(size_t)a1 * 16 + l]);
        float2 g2 = __half22float2(s22[(size_t)a2 * 16 + l]);
        float2 g3 = __half22float2(s22[(size_t)a3 * 16 + l]);
        acc.x += (g0.x + g1.x) + (g2.x + g3.x);
        acc.y += (g0.y + g1.y) + (g2.y + g3.y);
    }
    for (; k + 4 <= end; k += 4) {
        int a = srcs[k + q];
        float2 g = __half22float2(s22[(size_t)a * 16 + l]);
        acc.x += g.x;
        acc.y += g.y;
    }
    int rem = end - k;
    if (q < rem) {
        int a = srcs[k + q];
        float2 g = __half22float2(s22[(size_t)a * 16 + l]);
        acc.x += g.x;
        acc.y += g.y;
    }
    acc.x += __shfl_xor(acc.x, 16, 64);
    acc.x += __shfl_xor(acc.x, 32, 64);
    acc.y += __shfl_xor(acc.y, 16, 64);
    acc.y += __shfl_xor(acc.y, 32, 64);

    float dv = dis[v];
    float2 bb = *(const float2*)(b2 + 2 * l);
    float t0 = dv * acc.x + bb.x;
    float t1 = dv * acc.y + bb.y;
    float h0 = t0 > 0.f ? t0 : (expf(t0) - 1.f);
    float h1 = t1 > 0.f ? t1 : (expf(t1) - 1.f);
    float2 wc = *(const float2*)(Wc + 2 * l);
    float p = h0 * wc.x + h1 * wc.y;
#pragma unroll
    for (int off = 8; off > 0; off >>= 1) p += __shfl_xor(p, off, 64);  // sum over 16 lanes
    if (j == 0) out[v] = p + bc[0];
}

extern "C" void kernel_launch(void* const* d_in, const int* in_sizes, int n_in,
                              void* d_out, int out_size, void* d_ws, size_t ws_size,
                              hipStream_t stream) {
    const float* x  = (const float*)d_in[0];
    const int*   ei = (const int*)d_in[1];
    const float* W1 = (const float*)d_in[2];
    const float* b1 = (const float*)d_in[3];
    const float* W2 = (const float*)d_in[4];
    const float* b2 = (const float*)d_in[5];
    const float* Wc = (const float*)d_in[6];
    const float* bc = (const float*)d_in[7];
    float* out = (float*)d_out;

    const int* row = ei;            // edge_index[0] = source
    const int* col = ei + N_EDGES;  // edge_index[1] = target

    char* ws = (char*)d_ws;
    int*    ptrb = (int*)   (ws + OFF_PTRB);
    int*    ptre = (int*)   (ws + OFF_PTRE);
    int*    gcur = (int*)   (ws + OFF_GCUR);
    float*  dis  = (float*) (ws + OFF_DIS);
    int*    srcs = (int*)   (ws + OFF_SRC);
    int*    part = (int*)   (ws + OFF_PART);
    __half* s1h  = (__half*)(ws + OFF_S1);    // aliases part (part dead before gemm1)
    __half* s2h  = (__half*)(ws + OFF_S2);

    bucket_init    <<<(NBUCK + 255) / 256, 256, 0, stream>>>(gcur);
    partition_edges<<<(N_EDGES + CHUNK - 1) / CHUNK, 256, 0, stream>>>(row, col, gcur, part);
    bucket_hist    <<<NBUCK, 256, 0, stream>>>(gcur, part, ptrb, ptre, dis);
    bucket_fill    <<<NBUCK, 256, 0, stream>>>(gcur, part, ptrb, srcs);

    gemm1  <<<(N_NODES + 63) / 64, 256, 0, stream>>>(x, W1, dis, s1h);
    gather1<<<N_NODES / 4, 256, 0, stream>>>(s1h, ptrb, ptre, srcs, dis, b1, W2, s2h);
    gather2<<<N_NODES / 4, 256, 0, stream>>>(s2h, ptrb, ptre, srcs, dis, b2, Wc, bc, out);
}

// Round 16
// 404.612 us; speedup vs baseline: 1.0321x; 1.0245x over previous
//
#include <hip/hip_runtime.h>
#include <hip/hip_fp16.h>
#include <math.h>

#define N_NODES 100000
#define N_EDGES 3200000
#define IN_CH   256
#define HID     64
#define OUTC    32
#define NBUCK   ((N_NODES + 127) / 128)   // 782 buckets of 128 nodes (bucket = dst >> 7)
#define CHUNK   4096                      // edges per partition block
#define EPT     16                        // edges per thread (CHUNK/256)
#define CAP     4608                      // bucket capacity: mean 4092, sigma ~64 -> +8 sigma

// ---------------- workspace layout (bytes) ----------------
static constexpr size_t align256(size_t x) { return (x + 255) & ~(size_t)255; }
static constexpr size_t OFF_PTRB = 0;                                          // N ints (segment start)
static constexpr size_t OFF_PTRE = OFF_PTRB + align256((size_t)N_NODES * 4);   // N ints (segment end)
static constexpr size_t OFF_GCUR = OFF_PTRE + align256((size_t)N_NODES * 4);   // NBUCK ints
static constexpr size_t OFF_DIS  = OFF_GCUR + align256((size_t)NBUCK * 4);     // N floats
static constexpr size_t OFF_SRC  = OFF_DIS  + align256((size_t)N_NODES * 4);   // NBUCK*CAP ints (bucket-padded)
static constexpr size_t OFF_PART = OFF_SRC  + align256((size_t)NBUCK * CAP * 4); // NBUCK*CAP ints (14.4 MB)
// s1h (N*64 halves = 12.8 MB) aliases PART (part dead after bucket_build, before gemm1)
static constexpr size_t OFF_S1   = OFF_PART;
static constexpr size_t OFF_S2   = OFF_PART + align256((size_t)NBUCK * CAP * 4);  // N*32 halves (6.4 MB)
// total ~52 MB

// ---------------- bucket cursor init: gcur[b] = b*CAP ----------------
__global__ __launch_bounds__(256) void bucket_init(int* __restrict__ gcur) {
    int b = blockIdx.x * 256 + threadIdx.x;
    if (b < NBUCK) gcur[b] = b * CAP;
}

// ---------------- phase A: partition edges into dst-buckets (single pass) --------
__global__ __launch_bounds__(256) void partition_edges(const int* __restrict__ row,
                                                       const int* __restrict__ col,
                                                       int* __restrict__ gcur,
                                                       int* __restrict__ part) {
    __shared__ int lhist[NBUCK];
    __shared__ int lbase[NBUCK];
    const int t  = threadIdx.x;
    const int e0 = blockIdx.x * CHUNK;
    for (int i = t; i < NBUCK; i += 256) lhist[i] = 0;
    __syncthreads();

    int pk[EPT], br[EPT];
#pragma unroll
    for (int i = 0; i < EPT; ++i) {
        int e = e0 + i * 256 + t;
        if (e < N_EDGES) {
            int d = col[e];
            int b = d >> 7;
            int r = atomicAdd(&lhist[b], 1);
            pk[i] = row[e] | ((d & 127) << 17);
            br[i] = b | (r << 10);           // b<1024, r<4096 -> fits
        } else {
            br[i] = -1;
        }
    }
    __syncthreads();

    const int off = (int)((blockIdx.x * 131u) % NBUCK);
    for (int i = t; i < NBUCK; i += 256) {
        int bb = i + off;
        if (bb >= NBUCK) bb -= NBUCK;
        int c = lhist[bb];
        lbase[bb] = (c > 0) ? atomicAdd(&gcur[bb], c) : 0;
    }
    __syncthreads();

#pragma unroll
    for (int i = 0; i < EPT; ++i) {
        if (br[i] >= 0) {
            int b = br[i] & 1023;
            int r = br[i] >> 10;
            part[lbase[b] + r] = pk[i];
        }
    }
}

// ---------------- phase B (FUSED): hist + LDS scan + fill + dis ------------------
// One pass reads part twice from L2 (hot) instead of two dispatches re-reading
// from cold; no global ptrb round-trip for the fill.
__global__ __launch_bounds__(256) void bucket_build(const int* __restrict__ gcur,
                                                    const int* __restrict__ part,
                                                    int* __restrict__ ptrb,
                                                    int* __restrict__ ptre,
                                                    float* __restrict__ dis,
                                                    int* __restrict__ srcs) {
    __shared__ int lh[128];      // per-node count
    __shared__ int lb[128];      // exclusive scan (bucket-local base)
    __shared__ int lcur[128];    // fill cursor
    const int b = blockIdx.x;
    const int t = threadIdx.x;
    if (t < 128) { lh[t] = 0; lcur[t] = 0; }
    __syncthreads();
    const int cnt = gcur[b] - b * CAP;
    const size_t pbase = (size_t)b * CAP;

    // pass 1: histogram
    for (int i = t; i < cnt; i += 256)
        atomicAdd(&lh[part[pbase + i] >> 17], 1);
    __syncthreads();

    // LDS exclusive scan over 128 nodes
    int val = (t < 128) ? lh[t] : 0;
    __shared__ int ls[128];
    if (t < 128) ls[t] = val;
    __syncthreads();
    for (int off = 1; off < 128; off <<= 1) {
        int add = (t >= off && t < 128) ? ls[t - off] : 0;
        __syncthreads();
        if (t < 128) ls[t] += add;
        __syncthreads();
    }
    if (t < 128) lb[t] = ls[t] - val;   // exclusive
    __syncthreads();

    // outputs
    int v = b * 128 + t;
    if (t < 128 && v < N_NODES) {
        ptrb[v] = b * CAP + lb[t];
        ptre[v] = b * CAP + lb[t] + val;
        dis[v]  = rsqrtf((float)val + 1.0f);   // +1 self-loop
    }

    // pass 2: scatter into per-node segments (part is L2-hot from pass 1)
    for (int i = t; i < cnt; i += 256) {
        int p    = part[pbase + i];
        int dlow = p >> 17;
        int src  = p & 0x1FFFF;
        int r    = atomicAdd(&lcur[dlow], 1);
        srcs[pbase + lb[dlow] + r] = src;
    }
}

// ---------------- GEMM1: s1h[n][j] = fp16(dis[n] * (x[n,:] @ W1[:,j])) ----------
__global__ __launch_bounds__(256) void gemm1(const float* __restrict__ x,
                                             const float* __restrict__ W1,
                                             const float* __restrict__ dis,
                                             __half* __restrict__ s1h) {
    __shared__ float wlds[64 * HID];   // 16 KB k-chunk of W1: [k_local][j]
    __shared__ float xlds[64 * 68];    // 17 KB x-tile: [row_local][k_local], stride 68

    const int t  = threadIdx.x;
    const int tx = t & 15;
    const int ty = t >> 4;
    const int row0 = blockIdx.x * 64;

    float acc[4][4] = {{0.f}};

    for (int kt = 0; kt < IN_CH / 64; ++kt) {
        {
            const float4* w4 = (const float4*)(W1 + (size_t)kt * 64 * HID);
            float4* l4 = (float4*)wlds;
#pragma unroll
            for (int i = 0; i < 4; ++i) l4[i * 256 + t] = w4[i * 256 + t];
        }
        {
#pragma unroll
            for (int i = 0; i < 4; ++i) {
                int L  = i * 256 + t;
                int rl = L >> 4;
                int k4 = L & 15;
                int rg = row0 + rl;
                float4 v;
                if (rg < N_NODES) v = ((const float4*)x)[(size_t)rg * 64 + kt * 16 + k4];
                else              v = make_float4(0.f, 0.f, 0.f, 0.f);
                *(float4*)(&xlds[rl * 68 + k4 * 4]) = v;
            }
        }
        __syncthreads();

        const float4* wl4 = (const float4*)wlds;
#pragma unroll 4
        for (int k4 = 0; k4 < 16; ++k4) {
            float4 xv[4];
#pragma unroll
            for (int i = 0; i < 4; ++i)
                xv[i] = *(const float4*)(&xlds[(ty * 4 + i) * 68 + k4 * 4]);
#pragma unroll
            for (int kk = 0; kk < 4; ++kk) {
                float4 bv = wl4[(k4 * 4 + kk) * 16 + tx];
#pragma unroll
                for (int i = 0; i < 4; ++i) {
                    const float* xf = (const float*)&xv[i];
                    float a = xf[kk];
                    acc[i][0] += a * bv.x;
                    acc[i][1] += a * bv.y;
                    acc[i][2] += a * bv.z;
                    acc[i][3] += a * bv.w;
                }
            }
        }
        __syncthreads();
    }

#pragma unroll
    for (int i = 0; i < 4; ++i) {
        int rr = row0 + ty * 4 + i;
        if (rr < N_NODES) {
            float d = dis[rr];
            __half2 p0 = __floats2half2_rn(acc[i][0] * d, acc[i][1] * d);
            __half2 p1 = __floats2half2_rn(acc[i][2] * d, acc[i][3] * d);
            __half2* dst = (__half2*)(s1h + (size_t)rr * HID + tx * 4);
            dst[0] = p0;
            dst[1] = p1;
        }
    }
}

// ---------------- gather1 + ELU + fused GEMM2 -------------------------------------
// 2 edges/VMEM-instr; 8-edge main loop (4 loads in flight) — the r14 shape.
// 16-edge unroll regressed (r15: 72.6->85.8 us): deg~Poisson(32) puts ~25% of
// edges in the 1-load-in-flight tail at unroll 16 vs ~12% at unroll 8.
__global__ __launch_bounds__(256) void gather1(const __half* __restrict__ s1h,
                                               const int* __restrict__ ptrb,
                                               const int* __restrict__ ptre,
                                               const int* __restrict__ srcs,
                                               const float* __restrict__ dis,
                                               const float* __restrict__ b1,
                                               const float* __restrict__ W2,
                                               __half* __restrict__ s2h) {
    __shared__ float w2lds[HID * OUTC];   // 8 KB: [k][jo]
    __shared__ float hbuf[4][HID];        // per-wave ELU'd h row

    const int t = threadIdx.x;
    {
        float4* l4 = (float4*)w2lds;
        const float4* s4 = (const float4*)W2;
        l4[t] = s4[t];
        l4[256 + t] = s4[256 + t];
    }
    __syncthreads();

    const int j = t & 63;
    const int w = t >> 6;
    const int l = j & 31;                 // half2 index within row (features 2l,2l+1)
    const int h = j >> 5;                 // edge-of-pair selector
    const int v = __builtin_amdgcn_readfirstlane(blockIdx.x * 4 + w);
    const __half2* s12 = (const __half2*)s1h;   // row stride 32 half2

    float2 acc;
    {
        float2 self = __half22float2(s12[(size_t)v * 32 + l]);
        acc = (h == 0) ? self : make_float2(0.f, 0.f);   // self-loop counted once
    }
    const int beg = ptrb[v];
    const int end = ptre[v];
    int k = beg;
    for (; k + 8 <= end; k += 8) {
        int u0 = srcs[k],     u1 = srcs[k + 1], u2 = srcs[k + 2], u3 = srcs[k + 3];
        int u4 = srcs[k + 4], u5 = srcs[k + 5], u6 = srcs[k + 6], u7 = srcs[k + 7];
        int a0 = (h == 0) ? u0 : u1;
        int a1 = (h == 0) ? u2 : u3;
        int a2 = (h == 0) ? u4 : u5;
        int a3 = (h == 0) ? u6 : u7;
        float2 g0 = __half22float2(s12[(size_t)a0 * 32 + l]);
        float2 g1 = __half22float2(s12[(size_t)a1 * 32 + l]);
        float2 g2 = __half22float2(s12[(size_t)a2 * 32 + l]);
        float2 g3 = __half22float2(s12[(size_t)a3 * 32 + l]);
        acc.x += (g0.x + g1.x) + (g2.x + g3.x);
        acc.y += (g0.y + g1.y) + (g2.y + g3.y);
    }
    for (; k + 2 <= end; k += 2) {
        int u0 = srcs[k], u1 = srcs[k + 1];
        int a = (h == 0) ? u0 : u1;
        float2 g = __half22float2(s12[(size_t)a * 32 + l]);
        acc.x += g.x;
        acc.y += g.y;
    }
    if (k < end && h == 0) {
        float2 g = __half22float2(s12[(size_t)srcs[k] * 32 + l]);
        acc.x += g.x;
        acc.y += g.y;
    }
    acc.x += __shfl_xor(acc.x, 32, 64);   // even-edge + odd-edge partials
    acc.y += __shfl_xor(acc.y, 32, 64);

    float dv = dis[v];
    float2 bb = *(const float2*)(b1 + 2 * l);
    float t0 = dv * acc.x + bb.x;
    float t1 = dv * acc.y + bb.y;
    float h0 = t0 > 0.f ? t0 : (expf(t0) - 1.f);
    float h1 = t1 > 0.f ? t1 : (expf(t1) - 1.f);
    if (h == 0) {
        hbuf[w][2 * l]     = h0;
        hbuf[w][2 * l + 1] = h1;
    }

    // ---- fused gemm2: s2[v][jo] = dis[v] * sum_k hh[k] * W2[k][jo]
    const int jo = j & 31;
    const int kb = (j >> 5) * 32;          // lower lanes: k 0..31, upper: 32..63
    float p = 0.f;
#pragma unroll
    for (int kk = 0; kk < 32; ++kk)
        p += hbuf[w][kb + kk] * w2lds[(kb + kk) * OUTC + jo];
    p += __shfl_xor(p, 32, 64);            // combine the two k-halves
    if (j < 32) {
        s2h[(size_t)v * OUTC + jo] = __float2half(dv * p);
    }
}

// ---------------- gather2 + ELU + final projection --------------------------------
// 4 edges/VMEM-instr; 8-edge main loop (2 quad-loads in flight).
__global__ __launch_bounds__(256) void gather2(const __half* __restrict__ s2h,
                                               const int* __restrict__ ptrb,
                                               const int* __restrict__ ptre,
                                               const int* __restrict__ srcs,
                                               const float* __restrict__ dis,
                                               const float* __restrict__ b2,
                                               const float* __restrict__ Wc,
                                               const float* __restrict__ bc,
                                               float* __restrict__ out) {
    const int j = threadIdx.x & 63;
    const int w = threadIdx.x >> 6;
    const int l = j & 15;                 // half2 index within row
    const int q = j >> 4;                 // edge-of-quad selector
    const int v = __builtin_amdgcn_readfirstlane(blockIdx.x * 4 + w);
    const __half2* s22 = (const __half2*)s2h;   // row stride 16 half2

    float2 acc;
    {
        float2 self = __half22float2(s22[(size_t)v * 16 + l]);
        acc = (q == 0) ? self : make_float2(0.f, 0.f);
    }
    const int beg = ptrb[v];
    const int end = ptre[v];
    int k = beg;
    for (; k + 8 <= end; k += 8) {
        int a0 = srcs[k + q];
        int a1 = srcs[k + 4 + q];
        float2 g0 = __half22float2(s22[(size_t)a0 * 16 + l]);
        float2 g1 = __half22float2(s22[(size_t)a1 * 16 + l]);
        acc.x += g0.x + g1.x;
        acc.y += g0.y + g1.y;
    }
    for (; k + 4 <= end; k += 4) {
        int a = srcs[k + q];
        float2 g = __half22float2(s22[(size_t)a * 16 + l]);
        acc.x += g.x;
        acc.y += g.y;
    }
    int rem = end - k;
    if (q < rem) {
        int a = srcs[k + q];
        float2 g = __half22float2(s22[(size_t)a * 16 + l]);
        acc.x += g.x;
        acc.y += g.y;
    }
    acc.x += __shfl_xor(acc.x, 16, 64);
    acc.x += __shfl_xor(acc.x, 32, 64);
    acc.y += __shfl_xor(acc.y, 16, 64);
    acc.y += __shfl_xor(acc.y, 32, 64);

    float dv = dis[v];
    float2 bb = *(const float2*)(b2 + 2 * l);
    float t0 = dv * acc.x + bb.x;
    float t1 = dv * acc.y + bb.y;
    float h0 = t0 > 0.f ? t0 : (expf(t0) - 1.f);
    float h1 = t1 > 0.f ? t1 : (expf(t1) - 1.f);
    float2 wc = *(const float2*)(Wc + 2 * l);
    float p = h0 * wc.x + h1 * wc.y;
#pragma unroll
    for (int off = 8; off > 0; off >>= 1) p += __shfl_xor(p, off, 64);  // sum over 16 lanes
    if (j == 0) out[v] = p + bc[0];
}

extern "C" void kernel_launch(void* const* d_in, const int* in_sizes, int n_in,
                              void* d_out, int out_size, void* d_ws, size_t ws_size,
                              hipStream_t stream) {
    const float* x  = (const float*)d_in[0];
    const int*   ei = (const int*)d_in[1];
    const float* W1 = (const float*)d_in[2];
    const float* b1 = (const float*)d_in[3];
    const float* W2 = (const float*)d_in[4];
    const float* b2 = (const float*)d_in[5];
    const float* Wc = (const float*)d_in[6];
    const float* bc = (const float*)d_in[7];
    float* out = (float*)d_out;

    const int* row = ei;            // edge_index[0] = source
    const int* col = ei + N_EDGES;  // edge_index[1] = target

    char* ws = (char*)d_ws;
    int*    ptrb = (int*)   (ws + OFF_PTRB);
    int*    ptre = (int*)   (ws + OFF_PTRE);
    int*    gcur = (int*)   (ws + OFF_GCUR);
    float*  dis  = (float*) (ws + OFF_DIS);
    int*    srcs = (int*)   (ws + OFF_SRC);
    int*    part = (int*)   (ws + OFF_PART);
    __half* s1h  = (__half*)(ws + OFF_S1);    // aliases part (part dead before gemm1)
    __half* s2h  = (__half*)(ws + OFF_S2);

    bucket_init    <<<(NBUCK + 255) / 256, 256, 0, stream>>>(gcur);
    partition_edges<<<(N_EDGES + CHUNK - 1) / CHUNK, 256, 0, stream>>>(row, col, gcur, part);
    bucket_build   <<<NBUCK, 256, 0, stream>>>(gcur, part, ptrb, ptre, dis, srcs);

    gemm1  <<<(N_NODES + 63) / 64, 256, 0, stream>>>(x, W1, dis, s1h);
    gather1<<<N_NODES / 4, 256, 0, stream>>>(s1h, ptrb, ptre, srcs, dis, b1, W2, s2h);
    gather2<<<N_NODES / 4, 256, 0, stream>>>(s2h, ptrb, ptre, srcs, dis, b2, Wc, bc, out);
}

// Round 17
// 400.673 us; speedup vs baseline: 1.0422x; 1.0098x over previous
//
#include <hip/hip_runtime.h>
#include <hip/hip_fp16.h>
#include <math.h>

#define N_NODES 100000
#define N_EDGES 3200000
#define IN_CH   256
#define HID     64
#define OUTC    32
#define NBUCK   ((N_NODES + 127) / 128)   // 782 buckets of 128 nodes (bucket = dst >> 7)
#define CHUNK   4096                      // edges per partition block
#define EPT     16                        // edges per thread (CHUNK/256)
#define CAP     4608                      // bucket capacity: mean 4092, sigma ~64 -> +8 sigma

// ---------------- workspace layout (bytes) ----------------
static constexpr size_t align256(size_t x) { return (x + 255) & ~(size_t)255; }
static constexpr size_t OFF_PTRB = 0;                                          // N ints (segment start)
static constexpr size_t OFF_PTRE = OFF_PTRB + align256((size_t)N_NODES * 4);   // N ints (segment end)
static constexpr size_t OFF_GCUR = OFF_PTRE + align256((size_t)N_NODES * 4);   // NBUCK ints
static constexpr size_t OFF_DIS  = OFF_GCUR + align256((size_t)NBUCK * 4);     // N floats
static constexpr size_t OFF_SRC  = OFF_DIS  + align256((size_t)N_NODES * 4);   // NBUCK*CAP ints (bucket-padded)
static constexpr size_t OFF_PART = OFF_SRC  + align256((size_t)NBUCK * CAP * 4); // NBUCK*CAP ints (14.4 MB)
// s1h (N*64 halves = 12.8 MB) aliases PART (part dead after bucket_build, before gemm1)
static constexpr size_t OFF_S1   = OFF_PART;
static constexpr size_t OFF_S2   = OFF_PART + align256((size_t)NBUCK * CAP * 4);  // N*32 halves (6.4 MB)
// total ~52 MB

// unpack one 16 B chunk (8 halves) and accumulate into 8 fp32 accumulators
__device__ __forceinline__ void acc8(float* acc, float4 raw) {
    const __half2* hp = (const __half2*)&raw;
    float2 f0 = __half22float2(hp[0]);
    float2 f1 = __half22float2(hp[1]);
    float2 f2 = __half22float2(hp[2]);
    float2 f3 = __half22float2(hp[3]);
    acc[0] += f0.x; acc[1] += f0.y; acc[2] += f1.x; acc[3] += f1.y;
    acc[4] += f2.x; acc[5] += f2.y; acc[6] += f3.x; acc[7] += f3.y;
}

// ---------------- bucket cursor init: gcur[b] = b*CAP ----------------
__global__ __launch_bounds__(256) void bucket_init(int* __restrict__ gcur) {
    int b = blockIdx.x * 256 + threadIdx.x;
    if (b < NBUCK) gcur[b] = b * CAP;
}

// ---------------- phase A: partition edges into dst-buckets (single pass) --------
__global__ __launch_bounds__(256) void partition_edges(const int* __restrict__ row,
                                                       const int* __restrict__ col,
                                                       int* __restrict__ gcur,
                                                       int* __restrict__ part) {
    __shared__ int lhist[NBUCK];
    __shared__ int lbase[NBUCK];
    const int t  = threadIdx.x;
    const int e0 = blockIdx.x * CHUNK;
    for (int i = t; i < NBUCK; i += 256) lhist[i] = 0;
    __syncthreads();

    int pk[EPT], br[EPT];
#pragma unroll
    for (int i = 0; i < EPT; ++i) {
        int e = e0 + i * 256 + t;
        if (e < N_EDGES) {
            int d = col[e];
            int b = d >> 7;
            int r = atomicAdd(&lhist[b], 1);
            pk[i] = row[e] | ((d & 127) << 17);
            br[i] = b | (r << 10);           // b<1024, r<4096 -> fits
        } else {
            br[i] = -1;
        }
    }
    __syncthreads();

    const int off = (int)((blockIdx.x * 131u) % NBUCK);
    for (int i = t; i < NBUCK; i += 256) {
        int bb = i + off;
        if (bb >= NBUCK) bb -= NBUCK;
        int c = lhist[bb];
        lbase[bb] = (c > 0) ? atomicAdd(&gcur[bb], c) : 0;
    }
    __syncthreads();

#pragma unroll
    for (int i = 0; i < EPT; ++i) {
        if (br[i] >= 0) {
            int b = br[i] & 1023;
            int r = br[i] >> 10;
            part[lbase[b] + r] = pk[i];
        }
    }
}

// ---------------- phase B (FUSED): hist + LDS scan + fill + dis ------------------
__global__ __launch_bounds__(256) void bucket_build(const int* __restrict__ gcur,
                                                    const int* __restrict__ part,
                                                    int* __restrict__ ptrb,
                                                    int* __restrict__ ptre,
                                                    float* __restrict__ dis,
                                                    int* __restrict__ srcs) {
    __shared__ int lh[128];      // per-node count
    __shared__ int lb[128];      // exclusive scan (bucket-local base)
    __shared__ int lcur[128];    // fill cursor
    const int b = blockIdx.x;
    const int t = threadIdx.x;
    if (t < 128) { lh[t] = 0; lcur[t] = 0; }
    __syncthreads();
    const int cnt = gcur[b] - b * CAP;
    const size_t pbase = (size_t)b * CAP;

    for (int i = t; i < cnt; i += 256)
        atomicAdd(&lh[part[pbase + i] >> 17], 1);
    __syncthreads();

    int val = (t < 128) ? lh[t] : 0;
    __shared__ int ls[128];
    if (t < 128) ls[t] = val;
    __syncthreads();
    for (int off = 1; off < 128; off <<= 1) {
        int add = (t >= off && t < 128) ? ls[t - off] : 0;
        __syncthreads();
        if (t < 128) ls[t] += add;
        __syncthreads();
    }
    if (t < 128) lb[t] = ls[t] - val;   // exclusive
    __syncthreads();

    int v = b * 128 + t;
    if (t < 128 && v < N_NODES) {
        ptrb[v] = b * CAP + lb[t];
        ptre[v] = b * CAP + lb[t] + val;
        dis[v]  = rsqrtf((float)val + 1.0f);   // +1 self-loop
    }

    for (int i = t; i < cnt; i += 256) {
        int p    = part[pbase + i];
        int dlow = p >> 17;
        int src  = p & 0x1FFFF;
        int r    = atomicAdd(&lcur[dlow], 1);
        srcs[pbase + lb[dlow] + r] = src;
    }
}

// ---------------- GEMM1: s1h[n][j] = fp16(dis[n] * (x[n,:] @ W1[:,j])) ----------
__global__ __launch_bounds__(256) void gemm1(const float* __restrict__ x,
                                             const float* __restrict__ W1,
                                             const float* __restrict__ dis,
                                             __half* __restrict__ s1h) {
    __shared__ float wlds[64 * HID];   // 16 KB k-chunk of W1: [k_local][j]
    __shared__ float xlds[64 * 68];    // 17 KB x-tile: [row_local][k_local], stride 68

    const int t  = threadIdx.x;
    const int tx = t & 15;
    const int ty = t >> 4;
    const int row0 = blockIdx.x * 64;

    float acc[4][4] = {{0.f}};

    for (int kt = 0; kt < IN_CH / 64; ++kt) {
        {
            const float4* w4 = (const float4*)(W1 + (size_t)kt * 64 * HID);
            float4* l4 = (float4*)wlds;
#pragma unroll
            for (int i = 0; i < 4; ++i) l4[i * 256 + t] = w4[i * 256 + t];
        }
        {
#pragma unroll
            for (int i = 0; i < 4; ++i) {
                int L  = i * 256 + t;
                int rl = L >> 4;
                int k4 = L & 15;
                int rg = row0 + rl;
                float4 v;
                if (rg < N_NODES) v = ((const float4*)x)[(size_t)rg * 64 + kt * 16 + k4];
                else              v = make_float4(0.f, 0.f, 0.f, 0.f);
                *(float4*)(&xlds[rl * 68 + k4 * 4]) = v;
            }
        }
        __syncthreads();

        const float4* wl4 = (const float4*)wlds;
#pragma unroll 4
        for (int k4 = 0; k4 < 16; ++k4) {
            float4 xv[4];
#pragma unroll
            for (int i = 0; i < 4; ++i)
                xv[i] = *(const float4*)(&xlds[(ty * 4 + i) * 68 + k4 * 4]);
#pragma unroll
            for (int kk = 0; kk < 4; ++kk) {
                float4 bv = wl4[(k4 * 4 + kk) * 16 + tx];
#pragma unroll
                for (int i = 0; i < 4; ++i) {
                    const float* xf = (const float*)&xv[i];
                    float a = xf[kk];
                    acc[i][0] += a * bv.x;
                    acc[i][1] += a * bv.y;
                    acc[i][2] += a * bv.z;
                    acc[i][3] += a * bv.w;
                }
            }
        }
        __syncthreads();
    }

#pragma unroll
    for (int i = 0; i < 4; ++i) {
        int rr = row0 + ty * 4 + i;
        if (rr < N_NODES) {
            float d = dis[rr];
            __half2 p0 = __floats2half2_rn(acc[i][0] * d, acc[i][1] * d);
            __half2 p1 = __floats2half2_rn(acc[i][2] * d, acc[i][3] * d);
            __half2* dst = (__half2*)(s1h + (size_t)rr * HID + tx * 4);
            dst[0] = p0;
            dst[1] = p1;
        }
    }
}

// ---------------- gather1 + ELU + fused GEMM2 -------------------------------------
// 8 EDGES PER VMEM INSTRUCTION: row = 128 B = 8 lanes x dwordx4. Lane l=j&7
// holds features 8l..8l+7; e=j>>3 is edge-of-octet. Main loop 16 edges
// (2 dwordx4 row-loads in flight); tail = 2 masked instructions. Edge-group
// partials combined via shfl_xor(8,16,32).
__global__ __launch_bounds__(256) void gather1(const __half* __restrict__ s1h,
                                               const int* __restrict__ ptrb,
                                               const int* __restrict__ ptre,
                                               const int* __restrict__ srcs,
                                               const float* __restrict__ dis,
                                               const float* __restrict__ b1,
                                               const float* __restrict__ W2,
                                               __half* __restrict__ s2h) {
    __shared__ float w2lds[HID * OUTC];   // 8 KB: [k][jo]
    __shared__ float hbuf[4][HID];        // per-wave ELU'd h row

    const int t = threadIdx.x;
    {
        float4* l4 = (float4*)w2lds;
        const float4* s4 = (const float4*)W2;
        l4[t] = s4[t];
        l4[256 + t] = s4[256 + t];
    }
    __syncthreads();

    const int j = t & 63;
    const int w = t >> 6;
    const int l = j & 7;                  // feature octet within row
    const int e = j >> 3;                 // edge-of-octet (0..7)
    const int v = __builtin_amdgcn_readfirstlane(blockIdx.x * 4 + w);
    const float4* s14 = (const float4*)s1h;   // row stride 8 float4s (128 B)

    float acc[8] = {0.f, 0.f, 0.f, 0.f, 0.f, 0.f, 0.f, 0.f};
    if (e == 0) acc8(acc, s14[(size_t)v * 8 + l]);   // self-loop counted once

    int k = ptrb[v];
    const int end = ptre[v];
    for (; k + 16 <= end; k += 16) {
        int a0 = srcs[k + e];
        int a1 = srcs[k + 8 + e];
        float4 r0 = s14[(size_t)a0 * 8 + l];
        float4 r1 = s14[(size_t)a1 * 8 + l];
        acc8(acc, r0);
        acc8(acc, r1);
    }
    {
        int rem = end - k;
        if (e < rem)     acc8(acc, s14[(size_t)srcs[k + e] * 8 + l]);
        if (8 + e < rem) acc8(acc, s14[(size_t)srcs[k + 8 + e] * 8 + l]);
    }
#pragma unroll
    for (int i = 0; i < 8; ++i) {
        acc[i] += __shfl_xor(acc[i], 8, 64);
        acc[i] += __shfl_xor(acc[i], 16, 64);
        acc[i] += __shfl_xor(acc[i], 32, 64);
    }

    float dv = dis[v];
    if (e == 0) {
        float4 ba = ((const float4*)b1)[2 * l];
        float4 bb = ((const float4*)b1)[2 * l + 1];
        const float* bf = (const float*)&ba;
        const float* bg = (const float*)&bb;
#pragma unroll
        for (int i = 0; i < 8; ++i) {
            float bias = (i < 4) ? bf[i] : bg[i - 4];
            float tt = dv * acc[i] + bias;
            hbuf[w][8 * l + i] = tt > 0.f ? tt : (expf(tt) - 1.f);
        }
    }

    // ---- fused gemm2: s2[v][jo] = dis[v] * sum_k hh[k] * W2[k][jo]
    const int jo = j & 31;
    const int kb = (j >> 5) * 32;          // lower lanes: k 0..31, upper: 32..63
    float p = 0.f;
#pragma unroll
    for (int kk = 0; kk < 32; ++kk)
        p += hbuf[w][kb + kk] * w2lds[(kb + kk) * OUTC + jo];
    p += __shfl_xor(p, 32, 64);            // combine the two k-halves
    if (j < 32) {
        s2h[(size_t)v * OUTC + jo] = __float2half(dv * p);
    }
}

// ---------------- gather2 + ELU + final projection --------------------------------
// 16 EDGES PER VMEM INSTRUCTION: row = 64 B = 4 lanes x dwordx4. Lane l=j&3
// holds features 8l..8l+7; e=j>>2 is edge-of-16. Main loop 32 edges (2 loads
// in flight); tail = 2 masked instructions. Combine via shfl_xor(4,8,16,32).
__global__ __launch_bounds__(256) void gather2(const __half* __restrict__ s2h,
                                               const int* __restrict__ ptrb,
                                               const int* __restrict__ ptre,
                                               const int* __restrict__ srcs,
                                               const float* __restrict__ dis,
                                               const float* __restrict__ b2,
                                               const float* __restrict__ Wc,
                                               const float* __restrict__ bc,
                                               float* __restrict__ out) {
    const int j = threadIdx.x & 63;
    const int w = threadIdx.x >> 6;
    const int l = j & 3;                  // feature octet within row
    const int e = j >> 2;                 // edge-of-16 (0..15)
    const int v = __builtin_amdgcn_readfirstlane(blockIdx.x * 4 + w);
    const float4* s24 = (const float4*)s2h;   // row stride 4 float4s (64 B)

    float acc[8] = {0.f, 0.f, 0.f, 0.f, 0.f, 0.f, 0.f, 0.f};
    if (e == 0) acc8(acc, s24[(size_t)v * 4 + l]);   // self-loop

    int k = ptrb[v];
    const int end = ptre[v];
    for (; k + 32 <= end; k += 32) {
        int a0 = srcs[k + e];
        int a1 = srcs[k + 16 + e];
        float4 r0 = s24[(size_t)a0 * 4 + l];
        float4 r1 = s24[(size_t)a1 * 4 + l];
        acc8(acc, r0);
        acc8(acc, r1);
    }
    {
        int rem = end - k;
        if (e < rem)      acc8(acc, s24[(size_t)srcs[k + e] * 4 + l]);
        if (16 + e < rem) acc8(acc, s24[(size_t)srcs[k + 16 + e] * 4 + l]);
    }
#pragma unroll
    for (int i = 0; i < 8; ++i) {
        acc[i] += __shfl_xor(acc[i], 4, 64);
        acc[i] += __shfl_xor(acc[i], 8, 64);
        acc[i] += __shfl_xor(acc[i], 16, 64);
        acc[i] += __shfl_xor(acc[i], 32, 64);
    }

    float dv = dis[v];
    float4 ba = ((const float4*)b2)[2 * l];
    float4 bb = ((const float4*)b2)[2 * l + 1];
    float4 wa = ((const float4*)Wc)[2 * l];
    float4 wb = ((const float4*)Wc)[2 * l + 1];
    const float* bf = (const float*)&ba;
    const float* bg = (const float*)&bb;
    const float* wf = (const float*)&wa;
    const float* wg = (const float*)&wb;
    float p = 0.f;
#pragma unroll
    for (int i = 0; i < 8; ++i) {
        float bias = (i < 4) ? bf[i] : bg[i - 4];
        float wc   = (i < 4) ? wf[i] : wg[i - 4];
        float tt = dv * acc[i] + bias;
        float hh = tt > 0.f ? tt : (expf(tt) - 1.f);
        p += hh * wc;
    }
    p += __shfl_xor(p, 1, 64);   // reduce over the 4 feature-lanes
    p += __shfl_xor(p, 2, 64);
    if (j == 0) out[v] = p + bc[0];
}

extern "C" void kernel_launch(void* const* d_in, const int* in_sizes, int n_in,
                              void* d_out, int out_size, void* d_ws, size_t ws_size,
                              hipStream_t stream) {
    const float* x  = (const float*)d_in[0];
    const int*   ei = (const int*)d_in[1];
    const float* W1 = (const float*)d_in[2];
    const float* b1 = (const float*)d_in[3];
    const float* W2 = (const float*)d_in[4];
    const float* b2 = (const float*)d_in[5];
    const float* Wc = (const float*)d_in[6];
    const float* bc = (const float*)d_in[7];
    float* out = (float*)d_out;

    const int* row = ei;            // edge_index[0] = source
    const int* col = ei + N_EDGES;  // edge_index[1] = target

    char* ws = (char*)d_ws;
    int*    ptrb = (int*)   (ws + OFF_PTRB);
    int*    ptre = (int*)   (ws + OFF_PTRE);
    int*    gcur = (int*)   (ws + OFF_GCUR);
    float*  dis  = (float*) (ws + OFF_DIS);
    int*    srcs = (int*)   (ws + OFF_SRC);
    int*    part = (int*)   (ws + OFF_PART);
    __half* s1h  = (__half*)(ws + OFF_S1);    // aliases part (part dead before gemm1)
    __half* s2h  = (__half*)(ws + OFF_S2);

    bucket_init    <<<(NBUCK + 255) / 256, 256, 0, stream>>>(gcur);
    partition_edges<<<(N_EDGES + CHUNK - 1) / CHUNK, 256, 0, stream>>>(row, col, gcur, part);
    bucket_build   <<<NBUCK, 256, 0, stream>>>(gcur, part, ptrb, ptre, dis, srcs);

    gemm1  <<<(N_NODES + 63) / 64, 256, 0, stream>>>(x, W1, dis, s1h);
    gather1<<<N_NODES / 4, 256, 0, stream>>>(s1h, ptrb, ptre, srcs, dis, b1, W2, s2h);
    gather2<<<N_NODES / 4, 256, 0, stream>>>(s2h, ptrb, ptre, srcs, dis, b2, Wc, bc, out);
}

// Round 18
// 395.989 us; speedup vs baseline: 1.0545x; 1.0118x over previous
//
#include <hip/hip_runtime.h>
#include <hip/hip_fp16.h>
#include <math.h>

#define N_NODES 100000
#define N_EDGES 3200000
#define IN_CH   256
#define HID     64
#define OUTC    32
#define NBUCK   ((N_NODES + 127) / 128)   // 782 buckets of 128 nodes (bucket = dst >> 7)
#define CHUNK   4096                      // edges per partition block
#define EPT     16                        // edges per thread (CHUNK/256)
#define CAP     4608                      // bucket capacity: mean 4092, sigma ~64 -> +8 sigma

// ---------------- workspace layout (bytes) ----------------
static constexpr size_t align256(size_t x) { return (x + 255) & ~(size_t)255; }
static constexpr size_t OFF_PTRB = 0;                                          // N ints (segment start)
static constexpr size_t OFF_PTRE = OFF_PTRB + align256((size_t)N_NODES * 4);   // N ints (segment end)
static constexpr size_t OFF_GCUR = OFF_PTRE + align256((size_t)N_NODES * 4);   // NBUCK ints
static constexpr size_t OFF_DIS  = OFF_GCUR + align256((size_t)NBUCK * 4);     // N floats
static constexpr size_t OFF_SRC  = OFF_DIS  + align256((size_t)N_NODES * 4);   // NBUCK*CAP ints (bucket-padded)
static constexpr size_t OFF_PART = OFF_SRC  + align256((size_t)NBUCK * CAP * 4); // NBUCK*CAP ints (14.4 MB)
// s1h (N*64 halves = 12.8 MB) aliases PART (part dead after bucket_build, before gemm1)
static constexpr size_t OFF_S1   = OFF_PART;
static constexpr size_t OFF_S2   = OFF_PART + align256((size_t)NBUCK * CAP * 4);  // N*32 halves (6.4 MB)
// total ~52 MB

// unpack one 16 B chunk (8 halves) and accumulate into 8 fp32 accumulators
__device__ __forceinline__ void acc8(float* acc, float4 raw) {
    const __half2* hp = (const __half2*)&raw;
    float2 f0 = __half22float2(hp[0]);
    float2 f1 = __half22float2(hp[1]);
    float2 f2 = __half22float2(hp[2]);
    float2 f3 = __half22float2(hp[3]);
    acc[0] += f0.x; acc[1] += f0.y; acc[2] += f1.x; acc[3] += f1.y;
    acc[4] += f2.x; acc[5] += f2.y; acc[6] += f3.x; acc[7] += f3.y;
}

// ---------------- bucket cursor init: gcur[b] = b*CAP ----------------
__global__ __launch_bounds__(256) void bucket_init(int* __restrict__ gcur) {
    int b = blockIdx.x * 256 + threadIdx.x;
    if (b < NBUCK) gcur[b] = b * CAP;
}

// ---------------- phase A: partition edges into dst-buckets (single pass) --------
__global__ __launch_bounds__(256) void partition_edges(const int* __restrict__ row,
                                                       const int* __restrict__ col,
                                                       int* __restrict__ gcur,
                                                       int* __restrict__ part) {
    __shared__ int lhist[NBUCK];
    __shared__ int lbase[NBUCK];
    const int t  = threadIdx.x;
    const int e0 = blockIdx.x * CHUNK;
    for (int i = t; i < NBUCK; i += 256) lhist[i] = 0;
    __syncthreads();

    int pk[EPT], br[EPT];
#pragma unroll
    for (int i = 0; i < EPT; ++i) {
        int e = e0 + i * 256 + t;
        if (e < N_EDGES) {
            int d = col[e];
            int b = d >> 7;
            int r = atomicAdd(&lhist[b], 1);
            pk[i] = row[e] | ((d & 127) << 17);
            br[i] = b | (r << 10);           // b<1024, r<4096 -> fits
        } else {
            br[i] = -1;
        }
    }
    __syncthreads();

    const int off = (int)((blockIdx.x * 131u) % NBUCK);
    for (int i = t; i < NBUCK; i += 256) {
        int bb = i + off;
        if (bb >= NBUCK) bb -= NBUCK;
        int c = lhist[bb];
        lbase[bb] = (c > 0) ? atomicAdd(&gcur[bb], c) : 0;
    }
    __syncthreads();

#pragma unroll
    for (int i = 0; i < EPT; ++i) {
        if (br[i] >= 0) {
            int b = br[i] & 1023;
            int r = br[i] >> 10;
            part[lbase[b] + r] = pk[i];
        }
    }
}

// ---------------- phase B (FUSED): hist + LDS scan + fill + dis ------------------
__global__ __launch_bounds__(256) void bucket_build(const int* __restrict__ gcur,
                                                    const int* __restrict__ part,
                                                    int* __restrict__ ptrb,
                                                    int* __restrict__ ptre,
                                                    float* __restrict__ dis,
                                                    int* __restrict__ srcs) {
    __shared__ int lh[128];      // per-node count
    __shared__ int lb[128];      // exclusive scan (bucket-local base)
    __shared__ int lcur[128];    // fill cursor
    const int b = blockIdx.x;
    const int t = threadIdx.x;
    if (t < 128) { lh[t] = 0; lcur[t] = 0; }
    __syncthreads();
    const int cnt = gcur[b] - b * CAP;
    const size_t pbase = (size_t)b * CAP;

    for (int i = t; i < cnt; i += 256)
        atomicAdd(&lh[part[pbase + i] >> 17], 1);
    __syncthreads();

    int val = (t < 128) ? lh[t] : 0;
    __shared__ int ls[128];
    if (t < 128) ls[t] = val;
    __syncthreads();
    for (int off = 1; off < 128; off <<= 1) {
        int add = (t >= off && t < 128) ? ls[t - off] : 0;
        __syncthreads();
        if (t < 128) ls[t] += add;
        __syncthreads();
    }
    if (t < 128) lb[t] = ls[t] - val;   // exclusive
    __syncthreads();

    int v = b * 128 + t;
    if (t < 128 && v < N_NODES) {
        ptrb[v] = b * CAP + lb[t];
        ptre[v] = b * CAP + lb[t] + val;
        dis[v]  = rsqrtf((float)val + 1.0f);   // +1 self-loop
    }

    for (int i = t; i < cnt; i += 256) {
        int p    = part[pbase + i];
        int dlow = p >> 17;
        int src  = p & 0x1FFFF;
        int r    = atomicAdd(&lcur[dlow], 1);
        srcs[pbase + lb[dlow] + r] = src;
    }
}

// ---------------- GEMM1: s1h[n][j] = fp16(dis[n] * (x[n,:] @ W1[:,j])) ----------
__global__ __launch_bounds__(256) void gemm1(const float* __restrict__ x,
                                             const float* __restrict__ W1,
                                             const float* __restrict__ dis,
                                             __half* __restrict__ s1h) {
    __shared__ float wlds[64 * HID];   // 16 KB k-chunk of W1: [k_local][j]
    __shared__ float xlds[64 * 68];    // 17 KB x-tile: [row_local][k_local], stride 68

    const int t  = threadIdx.x;
    const int tx = t & 15;
    const int ty = t >> 4;
    const int row0 = blockIdx.x * 64;

    float acc[4][4] = {{0.f}};

    for (int kt = 0; kt < IN_CH / 64; ++kt) {
        {
            const float4* w4 = (const float4*)(W1 + (size_t)kt * 64 * HID);
            float4* l4 = (float4*)wlds;
#pragma unroll
            for (int i = 0; i < 4; ++i) l4[i * 256 + t] = w4[i * 256 + t];
        }
        {
#pragma unroll
            for (int i = 0; i < 4; ++i) {
                int L  = i * 256 + t;
                int rl = L >> 4;
                int k4 = L & 15;
                int rg = row0 + rl;
                float4 v;
                if (rg < N_NODES) v = ((const float4*)x)[(size_t)rg * 64 + kt * 16 + k4];
                else              v = make_float4(0.f, 0.f, 0.f, 0.f);
                *(float4*)(&xlds[rl * 68 + k4 * 4]) = v;
            }
        }
        __syncthreads();

        const float4* wl4 = (const float4*)wlds;
#pragma unroll 4
        for (int k4 = 0; k4 < 16; ++k4) {
            float4 xv[4];
#pragma unroll
            for (int i = 0; i < 4; ++i)
                xv[i] = *(const float4*)(&xlds[(ty * 4 + i) * 68 + k4 * 4]);
#pragma unroll
            for (int kk = 0; kk < 4; ++kk) {
                float4 bv = wl4[(k4 * 4 + kk) * 16 + tx];
#pragma unroll
                for (int i = 0; i < 4; ++i) {
                    const float* xf = (const float*)&xv[i];
                    float a = xf[kk];
                    acc[i][0] += a * bv.x;
                    acc[i][1] += a * bv.y;
                    acc[i][2] += a * bv.z;
                    acc[i][3] += a * bv.w;
                }
            }
        }
        __syncthreads();
    }

#pragma unroll
    for (int i = 0; i < 4; ++i) {
        int rr = row0 + ty * 4 + i;
        if (rr < N_NODES) {
            float d = dis[rr];
            __half2 p0 = __floats2half2_rn(acc[i][0] * d, acc[i][1] * d);
            __half2 p1 = __floats2half2_rn(acc[i][2] * d, acc[i][3] * d);
            __half2* dst = (__half2*)(s1h + (size_t)rr * HID + tx * 4);
            dst[0] = p0;
            dst[1] = p1;
        }
    }
}

// ---------------- gather1 + ELU + fused GEMM2 -------------------------------------
// r16 shape EXACTLY (73.2 us): 2 edges/VMEM-instr via __half2 lanes, 8-edge
// main loop (4 loads in flight). The r17 8-edge/dwordx4 variant regressed to
// 81.7 us: full-16B unpack (8 cvt+8 add/load) + 3-step shfl tree + strided
// hbuf writes (200K LDS conflicts) tipped the kernel VALU-bound (66% busy).
__global__ __launch_bounds__(256) void gather1(const __half* __restrict__ s1h,
                                               const int* __restrict__ ptrb,
                                               const int* __restrict__ ptre,
                                               const int* __restrict__ srcs,
                                               const float* __restrict__ dis,
                                               const float* __restrict__ b1,
                                               const float* __restrict__ W2,
                                               __half* __restrict__ s2h) {
    __shared__ float w2lds[HID * OUTC];   // 8 KB: [k][jo]
    __shared__ float hbuf[4][HID];        // per-wave ELU'd h row

    const int t = threadIdx.x;
    {
        float4* l4 = (float4*)w2lds;
        const float4* s4 = (const float4*)W2;
        l4[t] = s4[t];
        l4[256 + t] = s4[256 + t];
    }
    __syncthreads();

    const int j = t & 63;
    const int w = t >> 6;
    const int l = j & 31;                 // half2 index within row (features 2l,2l+1)
    const int h = j >> 5;                 // edge-of-pair selector
    const int v = __builtin_amdgcn_readfirstlane(blockIdx.x * 4 + w);
    const __half2* s12 = (const __half2*)s1h;   // row stride 32 half2

    float2 acc;
    {
        float2 self = __half22float2(s12[(size_t)v * 32 + l]);
        acc = (h == 0) ? self : make_float2(0.f, 0.f);   // self-loop counted once
    }
    const int beg = ptrb[v];
    const int end = ptre[v];
    int k = beg;
    for (; k + 8 <= end; k += 8) {
        int u0 = srcs[k],     u1 = srcs[k + 1], u2 = srcs[k + 2], u3 = srcs[k + 3];
        int u4 = srcs[k + 4], u5 = srcs[k + 5], u6 = srcs[k + 6], u7 = srcs[k + 7];
        int a0 = (h == 0) ? u0 : u1;
        int a1 = (h == 0) ? u2 : u3;
        int a2 = (h == 0) ? u4 : u5;
        int a3 = (h == 0) ? u6 : u7;
        float2 g0 = __half22float2(s12[(size_t)a0 * 32 + l]);
        float2 g1 = __half22float2(s12[(size_t)a1 * 32 + l]);
        float2 g2 = __half22float2(s12[(size_t)a2 * 32 + l]);
        float2 g3 = __half22float2(s12[(size_t)a3 * 32 + l]);
        acc.x += (g0.x + g1.x) + (g2.x + g3.x);
        acc.y += (g0.y + g1.y) + (g2.y + g3.y);
    }
    for (; k + 2 <= end; k += 2) {
        int u0 = srcs[k], u1 = srcs[k + 1];
        int a = (h == 0) ? u0 : u1;
        float2 g = __half22float2(s12[(size_t)a * 32 + l]);
        acc.x += g.x;
        acc.y += g.y;
    }
    if (k < end && h == 0) {
        float2 g = __half22float2(s12[(size_t)srcs[k] * 32 + l]);
        acc.x += g.x;
        acc.y += g.y;
    }
    acc.x += __shfl_xor(acc.x, 32, 64);   // even-edge + odd-edge partials
    acc.y += __shfl_xor(acc.y, 32, 64);

    float dv = dis[v];
    float2 bb = *(const float2*)(b1 + 2 * l);
    float t0 = dv * acc.x + bb.x;
    float t1 = dv * acc.y + bb.y;
    float h0 = t0 > 0.f ? t0 : (expf(t0) - 1.f);
    float h1 = t1 > 0.f ? t1 : (expf(t1) - 1.f);
    if (h == 0) {
        hbuf[w][2 * l]     = h0;
        hbuf[w][2 * l + 1] = h1;
    }

    // ---- fused gemm2: s2[v][jo] = dis[v] * sum_k hh[k] * W2[k][jo]
    const int jo = j & 31;
    const int kb = (j >> 5) * 32;          // lower lanes: k 0..31, upper: 32..63
    float p = 0.f;
#pragma unroll
    for (int kk = 0; kk < 32; ++kk)
        p += hbuf[w][kb + kk] * w2lds[(kb + kk) * OUTC + jo];
    p += __shfl_xor(p, 32, 64);            // combine the two k-halves
    if (j < 32) {
        s2h[(size_t)v * OUTC + jo] = __float2half(dv * p);
    }
}

// ---------------- gather2 + ELU + final projection --------------------------------
// r17 shape (KEPT — the 16-edge/dwordx4 packing won here): row = 64 B =
// 4 lanes x dwordx4; e=j>>2 edge-of-16; combine shfl_xor(4,8,16,32).
__global__ __launch_bounds__(256) void gather2(const __half* __restrict__ s2h,
                                               const int* __restrict__ ptrb,
                                               const int* __restrict__ ptre,
                                               const int* __restrict__ srcs,
                                               const float* __restrict__ dis,
                                               const float* __restrict__ b2,
                                               const float* __restrict__ Wc,
                                               const float* __restrict__ bc,
                                               float* __restrict__ out) {
    const int j = threadIdx.x & 63;
    const int w = threadIdx.x >> 6;
    const int l = j & 3;                  // feature octet within row
    const int e = j >> 2;                 // edge-of-16 (0..15)
    const int v = __builtin_amdgcn_readfirstlane(blockIdx.x * 4 + w);
    const float4* s24 = (const float4*)s2h;   // row stride 4 float4s (64 B)

    float acc[8] = {0.f, 0.f, 0.f, 0.f, 0.f, 0.f, 0.f, 0.f};
    if (e == 0) acc8(acc, s24[(size_t)v * 4 + l]);   // self-loop

    int k = ptrb[v];
    const int end = ptre[v];
    for (; k + 32 <= end; k += 32) {
        int a0 = srcs[k + e];
        int a1 = srcs[k + 16 + e];
        float4 r0 = s24[(size_t)a0 * 4 + l];
        float4 r1 = s24[(size_t)a1 * 4 + l];
        acc8(acc, r0);
        acc8(acc, r1);
    }
    {
        int rem = end - k;
        if (e < rem)      acc8(acc, s24[(size_t)srcs[k + e] * 4 + l]);
        if (16 + e < rem) acc8(acc, s24[(size_t)srcs[k + 16 + e] * 4 + l]);
    }
#pragma unroll
    for (int i = 0; i < 8; ++i) {
        acc[i] += __shfl_xor(acc[i], 4, 64);
        acc[i] += __shfl_xor(acc[i], 8, 64);
        acc[i] += __shfl_xor(acc[i], 16, 64);
        acc[i] += __shfl_xor(acc[i], 32, 64);
    }

    float dv = dis[v];
    float4 ba = ((const float4*)b2)[2 * l];
    float4 bb = ((const float4*)b2)[2 * l + 1];
    float4 wa = ((const float4*)Wc)[2 * l];
    float4 wb = ((const float4*)Wc)[2 * l + 1];
    const float* bf = (const float*)&ba;
    const float* bg = (const float*)&bb;
    const float* wf = (const float*)&wa;
    const float* wg = (const float*)&wb;
    float p = 0.f;
#pragma unroll
    for (int i = 0; i < 8; ++i) {
        float bias = (i < 4) ? bf[i] : bg[i - 4];
        float wc   = (i < 4) ? wf[i] : wg[i - 4];
        float tt = dv * acc[i] + bias;
        float hh = tt > 0.f ? tt : (expf(tt) - 1.f);
        p += hh * wc;
    }
    p += __shfl_xor(p, 1, 64);   // reduce over the 4 feature-lanes
    p += __shfl_xor(p, 2, 64);
    if (j == 0) out[v] = p + bc[0];
}

extern "C" void kernel_launch(void* const* d_in, const int* in_sizes, int n_in,
                              void* d_out, int out_size, void* d_ws, size_t ws_size,
                              hipStream_t stream) {
    const float* x  = (const float*)d_in[0];
    const int*   ei = (const int*)d_in[1];
    const float* W1 = (const float*)d_in[2];
    const float* b1 = (const float*)d_in[3];
    const float* W2 = (const float*)d_in[4];
    const float* b2 = (const float*)d_in[5];
    const float* Wc = (const float*)d_in[6];
    const float* bc = (const float*)d_in[7];
    float* out = (float*)d_out;

    const int* row = ei;            // edge_index[0] = source
    const int* col = ei + N_EDGES;  // edge_index[1] = target

    char* ws = (char*)d_ws;
    int*    ptrb = (int*)   (ws + OFF_PTRB);
    int*    ptre = (int*)   (ws + OFF_PTRE);
    int*    gcur = (int*)   (ws + OFF_GCUR);
    float*  dis  = (float*) (ws + OFF_DIS);
    int*    srcs = (int*)   (ws + OFF_SRC);
    int*    part = (int*)   (ws + OFF_PART);
    __half* s1h  = (__half*)(ws + OFF_S1);    // aliases part (part dead before gemm1)
    __half* s2h  = (__half*)(ws + OFF_S2);

    bucket_init    <<<(NBUCK + 255) / 256, 256, 0, stream>>>(gcur);
    partition_edges<<<(N_EDGES + CHUNK - 1) / CHUNK, 256, 0, stream>>>(row, col, gcur, part);
    bucket_build   <<<NBUCK, 256, 0, stream>>>(gcur, part, ptrb, ptre, dis, srcs);

    gemm1  <<<(N_NODES + 63) / 64, 256, 0, stream>>>(x, W1, dis, s1h);
    gather1<<<N_NODES / 4, 256, 0, stream>>>(s1h, ptrb, ptre, srcs, dis, b1, W2, s2h);
    gather2<<<N_NODES / 4, 256, 0, stream>>>(s2h, ptrb, ptre, srcs, dis, b2, Wc, bc, out);
}